// Round 11
// baseline (493.962 us; speedup 1.0000x reference)
//
#include <hip/hip_runtime.h>
#include <cstdint>
#include <cstddef>

// ---------------- problem constants ----------------
#define SCALEQ 0.17677669529663689f // 32^-0.5

typedef _Float16 half_t;
typedef _Float16 half8   __attribute__((ext_vector_type(8)));
typedef _Float16 half4v  __attribute__((ext_vector_type(4)));
typedef float    float4v __attribute__((ext_vector_type(4)));

// intra-wave LDS RAW fence: drain ds ops, block scheduler motion across.
#define WAIT_LDS()                                                            \
  do {                                                                        \
    asm volatile("s_waitcnt lgkmcnt(0)" ::: "memory");                        \
    __builtin_amdgcn_sched_barrier(0);                                        \
  } while (0)

// ---------------- merged prep kernel ----------------
// xq[bd][65 rows][256 c] fp16: rows 0..63 = interior pixels, row 64 = zeros
// (conv padding source — no masking needed in the conv loop).
// Wt layout: phys = ((tap*16+og)*8+kh)*512 + l15*32 + c5.
__global__ __launch_bounds__(256) void prep_all(
    const float* __restrict__ x, const float* __restrict__ dwconv_w,
    const float* __restrict__ qkv_w, const float* __restrict__ proj_w,
    const float* __restrict__ rpb, half_t* __restrict__ xq,
    half_t* __restrict__ Wt, half_t* __restrict__ qw16,
    half_t* __restrict__ pw16, float* __restrict__ btab) {
  __shared__ float tile[128 * 65];
  const int blk = blockIdx.x, t = threadIdx.x;
  if (blk < 800) {
    const int bd = blk, b = bd / 100, d = bd % 100;
    if (t < 32) {                        // zero row 64 (padding source)
      half8 z = {};
      *(half8*)(xq + ((size_t)bd * 65 + 64) * 256 + t * 8) = z;
    }
    for (int hf = 0; hf < 2; ++hf) {
      for (int i = 0; i < 32; ++i) {
        int idx = i * 256 + t, c = idx >> 6, hw = idx & 63;
        tile[c * 65 + hw] = x[(size_t)((b * 256 + hf * 128 + c) * 100 + d) * 64 + hw];
      }
      __syncthreads();
#pragma unroll
      for (int i = 0; i < 4; ++i) {
        int chunk = i * 256 + t;           // [64 hw][16 c8]
        int hw = chunk >> 4, c8 = chunk & 15;
        half8 h;
#pragma unroll
        for (int j = 0; j < 8; ++j) h[j] = (half_t)tile[(c8 * 8 + j) * 65 + hw];
        *(half8*)(xq + ((size_t)bd * 65 + hw) * 256 + hf * 128 + c8 * 8) = h;
      }
      __syncthreads();
    }
  } else if (blk < 944) {        // convw: fragment-major layout
    const int base = (blk - 800) * 4096;
#pragma unroll
    for (int i = 0; i < 16; ++i) {
      int idx = base + i * 256 + t;
      int tap = idx >> 16;
      int og = (idx >> 12) & 15, kh = (idx >> 9) & 7;
      int l15o = (idx >> 5) & 15, c5 = idx & 31;
      int o = og * 16 + l15o, c = kh * 32 + c5;
      Wt[idx] = (half_t)dwconv_w[(o * 256 + c) * 9 + tap];
    }
  } else if (blk < 1040) {       // qkvw (q rows pre-scaled)
    const int base = (blk - 944) * 2048;
#pragma unroll
    for (int i = 0; i < 8; ++i) {
      int idx = base + i * 256 + t;
      float v = qkv_w[idx];
      if (idx < 65536) v *= SCALEQ;
      qw16[idx] = (half_t)v;
    }
  } else if (blk < 1072) {       // projw
    const int base = (blk - 1040) * 2048;
#pragma unroll
    for (int i = 0; i < 8; ++i) {
      int idx = base + i * 256 + t;
      pw16[idx] = (half_t)proj_w[idx];
    }
  } else {                       // bias table btab[head][n][m]
    const int base = (blk - 1072) * 2048;
#pragma unroll
    for (int i = 0; i < 8; ++i) {
      int idx = base + i * 256 + t;
      int hd = idx >> 12, n = (idx >> 6) & 63, m = idx & 63;
      int h1 = n >> 3, w1 = n & 7, h2 = m >> 3, w2 = m & 7;
      int ridx = (h1 - h2 + 7) * 15 + (w1 - w2 + 7);
      btab[idx] = rpb[ridx * 8 + hd];
    }
  }
}

// ---------------- fully fused, 3 blocks/CU (LDS 53248 B) ----------------
// grid 800, block 512 (8 waves = 1 wave per head).
// Body = r8's (verified correct): global conv-B reads from xq, per-wave
// scratch stride 1280 halfs = 2560 B (q/k transpose [32][40]=1280 halfs
// is the peak use — r10's 640-half stride caused cross-wave collisions).
// ONLY change vs r8: waves_per_eu(4) — min 4 (VGPR budget 128, natural
// pressure ~64, no spills), NO max cap, so the LDS-limited 3 blocks/CU
// can run 6 waves/SIMD. r8's (6,6) forced a 40-VGPR budget -> spills.
__global__ __launch_bounds__(512)
__attribute__((amdgpu_waves_per_eu(4))) void fused_all(
    const half_t* __restrict__ xqg, const half_t* __restrict__ Wt,
    const float* __restrict__ convb, const half_t* __restrict__ qw,
    const float* __restrict__ qkvb, const float* __restrict__ btab,
    const half_t* __restrict__ pw, const float* __restrict__ projb,
    float* __restrict__ out32) {
  __shared__ __align__(16) half_t LS[26624];   // 53248 B
  const int bd = blockIdx.x;
  const int tid = threadIdx.x;
  const int wave = tid >> 6, lane = tid & 63;
  const int l15 = lane & 15, quad = lane >> 4;
  const int head = wave;

  half_t* xlp = LS;                          // [64 px][256 o] swizzled
  half_t* xa = LS;                           // [64][264] overlay after PV barrier
  float* T = (float*)LS;                     // [64][68] fp32 overlay at the end
  half_t* buf = LS + 16384 + wave * 1280;    // 2560 B per-wave scratch

  const half_t* Wq0 = qw + head * 32 * 256;
  const half_t* Wk0 = qw + 65536 + head * 32 * 256;
  const half_t* Wv0 = qw + 131072 + head * 32 * 256;
  const half_t* xb = xqg + (size_t)bd * 16640;   // [65][256]

  // ---- conv implicit GEMM: wave owns o in [wave*32,+32), px 0..63.
  //      B-fragments from global xq (L1/L2-hot); A from Wt (L2-hot). ----
  {
    const int wwl = l15 & 7, hb = l15 >> 3;
    float4v acc[2][4];
#pragma unroll
    for (int mi = 0; mi < 2; ++mi)
#pragma unroll
      for (int ni = 0; ni < 4; ++ni) {
        float4v z = {0.f, 0.f, 0.f, 0.f};
        acc[mi][ni] = z;
      }
    const half_t* wv0 = Wt + (wave * 2) * 4096 + l15 * 32 + quad * 8;
#pragma unroll 1
    for (int tap = 0; tap < 9; ++tap) {
      const int th = tap / 3, tw = tap - th * 3;
      const half_t* wt = wv0 + tap * 65536;
      const int ww = wwl + tw;
      const int okw = (ww >= 1) & (ww <= 8);
      int rowv[4];
#pragma unroll
      for (int ni = 0; ni < 4; ++ni) {
        const int hh = hb + th + ni * 2;
        const int ok = okw & (hh >= 1) & (hh <= 8);
        rowv[ni] = ok ? ((hh - 1) * 8 + (ww - 1)) : 64;   // 64 = zero row
      }
#pragma unroll
      for (int kh = 0; kh < 8; ++kh) {
        half8 af0 = *(const half8*)(wt + kh * 512);
        half8 af1 = *(const half8*)(wt + 4096 + kh * 512);
        half8 bf[4];
#pragma unroll
        for (int ni = 0; ni < 4; ++ni)
          bf[ni] = *(const half8*)(xb + rowv[ni] * 256 + kh * 32 + quad * 8);
#pragma unroll
        for (int ni = 0; ni < 4; ++ni) {
          acc[0][ni] = __builtin_amdgcn_mfma_f32_16x16x32_f16(af0, bf[ni], acc[0][ni], 0, 0, 0);
          acc[1][ni] = __builtin_amdgcn_mfma_f32_16x16x32_f16(af1, bf[ni], acc[1][ni], 0, 0, 0);
        }
      }
    }
    // epilogue: +bias, fp16, store xl[px][o] with the qkv-expected swizzle
#pragma unroll
    for (int mi = 0; mi < 2; ++mi) {
      const int o4 = wave * 32 + mi * 16 + quad * 4;
      const float4v b4 = *(const float4v*)&convb[o4];
      const int chunk = o4 >> 3;
      const int sub = (quad & 1) * 4;
#pragma unroll
      for (int ni = 0; ni < 4; ++ni) {
        const int px = ni * 16 + l15;
        half4v h;
        h.x = (half_t)(acc[mi][ni].x + b4.x);
        h.y = (half_t)(acc[mi][ni].y + b4.y);
        h.z = (half_t)(acc[mi][ni].z + b4.z);
        h.w = (half_t)(acc[mi][ni].w + b4.w);
        *(half4v*)&xlp[px * 256 + ((chunk ^ (px & 7)) * 8) + sub] = h;
      }
    }
  }

  __syncthreads();   // xl complete; scratch region becomes per-wave buf

  // ---- q GEMM: weights per-kh direct from L2; transpose via 2 row-halves ----
  half8 aq[4];
  {
    float4v acc[2][4];
#pragma unroll
    for (int mi = 0; mi < 2; ++mi)
#pragma unroll
      for (int ni = 0; ni < 4; ++ni) {
        float4v z = {0.f, 0.f, 0.f, 0.f};
        acc[mi][ni] = z;
      }
#pragma unroll
    for (int kh = 0; kh < 8; ++kh) {
      half8 w0 = *(const half8*)(Wq0 + l15 * 256 + kh * 32 + quad * 8);
      half8 w1 = *(const half8*)(Wq0 + (16 + l15) * 256 + kh * 32 + quad * 8);
      half8 bf[4];
#pragma unroll
      for (int ni = 0; ni < 4; ++ni) {
        int r = ni * 16 + l15;
        bf[ni] = *(const half8*)&xlp[r * 256 + (((kh * 4 + quad) ^ (r & 7)) * 8)];
      }
#pragma unroll
      for (int ni = 0; ni < 4; ++ni) {
        acc[0][ni] = __builtin_amdgcn_mfma_f32_16x16x32_f16(w0, bf[ni], acc[0][ni], 0, 0, 0);
        acc[1][ni] = __builtin_amdgcn_mfma_f32_16x16x32_f16(w1, bf[ni], acc[1][ni], 0, 0, 0);
      }
    }
#pragma unroll
    for (int h2 = 0; h2 < 2; ++h2) {       // rows h2*32 .. +31 through buf[32][40]
#pragma unroll
      for (int mi = 0; mi < 2; ++mi) {
        const float4v b4 = *(const float4v*)&qkvb[head * 32 + mi * 16 + quad * 4];
#pragma unroll
        for (int nj = 0; nj < 2; ++nj) {
          const int ni = h2 * 2 + nj;
          half4v h;
          h.x = (half_t)(acc[mi][ni].x + b4.x * SCALEQ);
          h.y = (half_t)(acc[mi][ni].y + b4.y * SCALEQ);
          h.z = (half_t)(acc[mi][ni].z + b4.z * SCALEQ);
          h.w = (half_t)(acc[mi][ni].w + b4.w * SCALEQ);
          *(half4v*)(buf + (nj * 16 + l15) * 40 + mi * 16 + quad * 4) = h;
        }
      }
      WAIT_LDS();
#pragma unroll
      for (int j = 0; j < 2; ++j)
        aq[h2 * 2 + j] = *(const half8*)(buf + (j * 16 + l15) * 40 + quad * 8);
      WAIT_LDS();
    }
  }

  // ---- k GEMM (same pattern) ----
  half8 bk[4];
  {
    float4v acc[2][4];
#pragma unroll
    for (int mi = 0; mi < 2; ++mi)
#pragma unroll
      for (int ni = 0; ni < 4; ++ni) {
        float4v z = {0.f, 0.f, 0.f, 0.f};
        acc[mi][ni] = z;
      }
#pragma unroll
    for (int kh = 0; kh < 8; ++kh) {
      half8 w0 = *(const half8*)(Wk0 + l15 * 256 + kh * 32 + quad * 8);
      half8 w1 = *(const half8*)(Wk0 + (16 + l15) * 256 + kh * 32 + quad * 8);
      half8 bf[4];
#pragma unroll
      for (int ni = 0; ni < 4; ++ni) {
        int r = ni * 16 + l15;
        bf[ni] = *(const half8*)&xlp[r * 256 + (((kh * 4 + quad) ^ (r & 7)) * 8)];
      }
#pragma unroll
      for (int ni = 0; ni < 4; ++ni) {
        acc[0][ni] = __builtin_amdgcn_mfma_f32_16x16x32_f16(w0, bf[ni], acc[0][ni], 0, 0, 0);
        acc[1][ni] = __builtin_amdgcn_mfma_f32_16x16x32_f16(w1, bf[ni], acc[1][ni], 0, 0, 0);
      }
    }
#pragma unroll
    for (int h2 = 0; h2 < 2; ++h2) {
#pragma unroll
      for (int mi = 0; mi < 2; ++mi) {
        const float4v b4 = *(const float4v*)&qkvb[256 + head * 32 + mi * 16 + quad * 4];
#pragma unroll
        for (int nj = 0; nj < 2; ++nj) {
          const int ni = h2 * 2 + nj;
          half4v h;
          h.x = (half_t)(acc[mi][ni].x + b4.x);
          h.y = (half_t)(acc[mi][ni].y + b4.y);
          h.z = (half_t)(acc[mi][ni].z + b4.z);
          h.w = (half_t)(acc[mi][ni].w + b4.w);
          *(half4v*)(buf + (nj * 16 + l15) * 40 + mi * 16 + quad * 4) = h;
        }
      }
      WAIT_LDS();
#pragma unroll
      for (int j = 0; j < 2; ++j)
        bk[h2 * 2 + j] = *(const half8*)(buf + (j * 16 + l15) * 40 + quad * 8);
      WAIT_LDS();
    }
  }

  // ---- v GEMM: transpose via 2 c-halves of buf[16][72]; av straight to regs ----
  half8 av[2][2];
  {
    float4v acc[2][4];
#pragma unroll
    for (int mi = 0; mi < 2; ++mi)
#pragma unroll
      for (int ni = 0; ni < 4; ++ni) {
        float4v z = {0.f, 0.f, 0.f, 0.f};
        acc[mi][ni] = z;
      }
#pragma unroll
    for (int kh = 0; kh < 8; ++kh) {
      half8 w0 = *(const half8*)(Wv0 + l15 * 256 + kh * 32 + quad * 8);
      half8 w1 = *(const half8*)(Wv0 + (16 + l15) * 256 + kh * 32 + quad * 8);
      half8 bf[4];
#pragma unroll
      for (int ni = 0; ni < 4; ++ni) {
        int r = ni * 16 + l15;
        bf[ni] = *(const half8*)&xlp[r * 256 + (((kh * 4 + quad) ^ (r & 7)) * 8)];
      }
#pragma unroll
      for (int ni = 0; ni < 4; ++ni) {
        acc[0][ni] = __builtin_amdgcn_mfma_f32_16x16x32_f16(w0, bf[ni], acc[0][ni], 0, 0, 0);
        acc[1][ni] = __builtin_amdgcn_mfma_f32_16x16x32_f16(w1, bf[ni], acc[1][ni], 0, 0, 0);
      }
    }
#pragma unroll
    for (int mi = 0; mi < 2; ++mi) {       // c-rows mi*16 .. +15 through buf[16][72]
      const float4v b4 = *(const float4v*)&qkvb[512 + head * 32 + mi * 16 + quad * 4];
#pragma unroll
      for (int ni = 0; ni < 4; ++ni)
#pragma unroll
        for (int iv = 0; iv < 4; ++iv)
          buf[(quad * 4 + iv) * 72 + ni * 16 + l15] =
              (half_t)(acc[mi][ni][iv] + b4[iv]);
      WAIT_LDS();
#pragma unroll
      for (int k2 = 0; k2 < 2; ++k2)
        av[mi][k2] = *(const half8*)(buf + l15 * 72 + k2 * 32 + quad * 8);
      WAIT_LDS();
    }
  }

  // ---- QK^T + bias (direct loads) + softmax ----
  const float* bh = btab + head * 4096;
  float4v s[4][4];
#pragma unroll
  for (int ni = 0; ni < 4; ++ni)
#pragma unroll
    for (int mi = 0; mi < 4; ++mi) {
      float4v z = {0.f, 0.f, 0.f, 0.f};
      s[ni][mi] = __builtin_amdgcn_mfma_f32_16x16x32_f16(aq[ni], bk[mi], z, 0, 0, 0);
    }
#pragma unroll
  for (int ni = 0; ni < 4; ++ni)
#pragma unroll
    for (int i = 0; i < 4; ++i) {
      const int n = ni * 16 + quad * 4 + i;
#pragma unroll
      for (int mi = 0; mi < 4; ++mi)
        s[ni][mi][i] += bh[n * 64 + mi * 16 + l15];
    }
  float inv[4][4];
#pragma unroll
  for (int ni = 0; ni < 4; ++ni)
#pragma unroll
    for (int i = 0; i < 4; ++i) {
      float mx = fmaxf(fmaxf(s[ni][0][i], s[ni][1][i]), fmaxf(s[ni][2][i], s[ni][3][i]));
      for (int off = 1; off < 16; off <<= 1) mx = fmaxf(mx, __shfl_xor(mx, off));
      float sum = 0.f;
#pragma unroll
      for (int mi = 0; mi < 4; ++mi) {
        float e = __expf(s[ni][mi][i] - mx);
        s[ni][mi][i] = e;
        sum += e;
      }
      for (int off = 1; off < 16; off <<= 1) sum += __shfl_xor(sum, off);
      inv[ni][i] = 1.0f / sum;
    }
  // pack P to fp16 in registers: frees s before PV
  half4v ph[4][4];
#pragma unroll
  for (int ni = 0; ni < 4; ++ni)
#pragma unroll
    for (int mi = 0; mi < 4; ++mi)
#pragma unroll
      for (int i = 0; i < 4; ++i)
        ph[ni][mi][i] = (half_t)(s[ni][mi][i] * inv[ni][i]);

  // ---- PV: P through buf[32][36] in 4 (k2 x row-half) rounds ----
  float4v oa[2][4];
#pragma unroll
  for (int ci = 0; ci < 2; ++ci)
#pragma unroll
    for (int ni = 0; ni < 4; ++ni) {
      float4v z = {0.f, 0.f, 0.f, 0.f};
      oa[ci][ni] = z;
    }
#pragma unroll
  for (int k2 = 0; k2 < 2; ++k2) {
#pragma unroll
    for (int rh = 0; rh < 2; ++rh) {       // P rows rh*32 .. +31
#pragma unroll
      for (int nj = 0; nj < 2; ++nj) {
        const int ni = rh * 2 + nj;
#pragma unroll
        for (int mi2 = 0; mi2 < 2; ++mi2) {
          const int mi = k2 * 2 + mi2;
#pragma unroll
          for (int i = 0; i < 4; ++i)
            buf[(nj * 16 + quad * 4 + i) * 36 + mi2 * 16 + l15] = ph[ni][mi][i];
        }
      }
      WAIT_LDS();
      half8 bpn[2];
#pragma unroll
      for (int nj = 0; nj < 2; ++nj)
        bpn[nj] = *(const half8*)(buf + (nj * 16 + l15) * 36 + quad * 8);
      WAIT_LDS();
#pragma unroll
      for (int nj = 0; nj < 2; ++nj)
#pragma unroll
        for (int ci = 0; ci < 2; ++ci)
          oa[ci][rh * 2 + nj] = __builtin_amdgcn_mfma_f32_16x16x32_f16(
              av[ci][k2], bpn[nj], oa[ci][rh * 2 + nj], 0, 0, 0);
    }
  }

  __syncthreads();  // all waves done reading xlp/buf -> xa may overwrite

  // ---- xa -> LDS [px][264] ----
#pragma unroll
  for (int ci = 0; ci < 2; ++ci)
#pragma unroll
    for (int ni = 0; ni < 4; ++ni) {
      half4v h = {(half_t)oa[ci][ni].x, (half_t)oa[ci][ni].y,
                  (half_t)oa[ci][ni].z, (half_t)oa[ci][ni].w};
      *(half4v*)(xa + (ni * 16 + l15) * 264 + head * 32 + ci * 16 + quad * 4) = h;
    }
  __syncthreads();

  // ---- proj: wave owns o-rows [32*wave,+32), weights per-kh from L2 ----
  const half_t* Wp0 = pw + wave * 32 * 256;
  float4v pacc[2][4];
#pragma unroll
  for (int mi = 0; mi < 2; ++mi)
#pragma unroll
    for (int ni = 0; ni < 4; ++ni) {
      float4v z = {0.f, 0.f, 0.f, 0.f};
      pacc[mi][ni] = z;
    }
#pragma unroll
  for (int kh = 0; kh < 8; ++kh) {
    half8 w0 = *(const half8*)(Wp0 + l15 * 256 + kh * 32 + quad * 8);
    half8 w1 = *(const half8*)(Wp0 + (16 + l15) * 256 + kh * 32 + quad * 8);
    half8 bf[4];
#pragma unroll
    for (int ni = 0; ni < 4; ++ni)
      bf[ni] = *(const half8*)&xa[(ni * 16 + l15) * 264 + kh * 32 + quad * 8];
#pragma unroll
    for (int ni = 0; ni < 4; ++ni) {
      pacc[0][ni] = __builtin_amdgcn_mfma_f32_16x16x32_f16(w0, bf[ni], pacc[0][ni], 0, 0, 0);
      pacc[1][ni] = __builtin_amdgcn_mfma_f32_16x16x32_f16(w1, bf[ni], pacc[1][ni], 0, 0, 0);
    }
  }
#pragma unroll
  for (int mi = 0; mi < 2; ++mi) {
    const float4v b4 = *(const float4v*)&projb[wave * 32 + mi * 16 + quad * 4];
#pragma unroll
    for (int ni = 0; ni < 4; ++ni) {
      pacc[mi][ni].x += b4.x;
      pacc[mi][ni].y += b4.y;
      pacc[mi][ni].z += b4.z;
      pacc[mi][ni].w += b4.w;
    }
  }

  // ---- transpose epilogue: 4 rounds of 64 o-rows via T[64][68] fp32 ----
  const int b = bd / 100, d = bd % 100;
  const size_t bdbase = (size_t)b * 1638400 + (size_t)d * 64;
  const int tr = tid >> 3;             // 0..63
  const int col0 = (tid & 7) * 4;      // 0..28
  for (int r = 0; r < 4; ++r) {
    __syncthreads();                   // r=0: also guards xa reads done
    if ((wave >> 1) == r) {
      const int rb = (wave & 1) * 32;
#pragma unroll
      for (int mi = 0; mi < 2; ++mi)
#pragma unroll
        for (int ni = 0; ni < 4; ++ni)
#pragma unroll
          for (int iv = 0; iv < 4; ++iv)
            T[(rb + mi * 16 + quad * 4 + iv) * 68 + ni * 16 + l15] = pacc[mi][ni][iv];
    }
    __syncthreads();
    const int o = r * 64 + tr;
    float* dst = out32 + bdbase + (size_t)o * 6400 + col0;
    const float* srcT = &T[tr * 68 + col0];
    float4v v0 = *(const float4v*)srcT;
    float4v v1 = *(const float4v*)(srcT + 32);
    __builtin_nontemporal_store(v0, (float4v*)dst);
    __builtin_nontemporal_store(v1, (float4v*)(dst + 32));
  }
}

// ---------------- launch ----------------
extern "C" void kernel_launch(void* const* d_in, const int* in_sizes, int n_in,
                              void* d_out, int out_size, void* d_ws, size_t ws_size,
                              hipStream_t stream) {
  const float* x        = (const float*)d_in[0];
  const float* dwconv_w = (const float*)d_in[1];
  const float* dwconv_b = (const float*)d_in[2];
  const float* qkv_w    = (const float*)d_in[3];
  const float* qkv_b    = (const float*)d_in[4];
  const float* proj_w   = (const float*)d_in[5];
  const float* proj_b   = (const float*)d_in[6];
  const float* rpb      = (const float*)d_in[7];
  float* out = (float*)d_out;

  char* ws = (char*)d_ws;
  size_t off = 0;
  half_t* xq   = (half_t*)(ws + off); off += 26624000;   // 800*[65][256] fp16
  half_t* Wt   = (half_t*)(ws + off); off += 1179648;    // [9][16og][8kh][16][32]
  half_t* qw16 = (half_t*)(ws + off); off += 393216;
  half_t* pw16 = (half_t*)(ws + off); off += 131072;
  float*  btab = (float*)(ws + off);  off += 131072;     // [8][64][64]

  prep_all<<<1088, 256, 0, stream>>>(x, dwconv_w, qkv_w, proj_w, rpb,
                                     xq, Wt, qw16, pw16, btab);
  fused_all<<<800, 512, 0, stream>>>(xq, Wt, dwconv_b, qw16, qkv_b, btab,
                                     pw16, proj_b, out);
}

// Round 12
// 255.575 us; speedup vs baseline: 1.9328x; 1.9328x over previous
//
#include <hip/hip_runtime.h>
#include <cstdint>
#include <cstddef>

// ---------------- problem constants ----------------
#define SCALEQ 0.17677669529663689f // 32^-0.5

typedef _Float16 half_t;
typedef _Float16 half8   __attribute__((ext_vector_type(8)));
typedef _Float16 half4v  __attribute__((ext_vector_type(4)));
typedef float    float4v __attribute__((ext_vector_type(4)));

// intra-wave LDS RAW fence: drain ds ops, block scheduler motion across.
#define WAIT_LDS()                                                            \
  do {                                                                        \
    asm volatile("s_waitcnt lgkmcnt(0)" ::: "memory");                        \
    __builtin_amdgcn_sched_barrier(0);                                        \
  } while (0)

// ---------------- weight-only prep kernel (288 blocks) ----------------
// Wt layout: phys = ((tap*16+og)*8+kh)*512 + l15*32 + c5.
__global__ __launch_bounds__(256) void prep_w(
    const float* __restrict__ dwconv_w, const float* __restrict__ qkv_w,
    const float* __restrict__ proj_w, const float* __restrict__ rpb,
    half_t* __restrict__ Wt, half_t* __restrict__ qw16,
    half_t* __restrict__ pw16, float* __restrict__ btab) {
  const int blk = blockIdx.x, t = threadIdx.x;
  if (blk < 144) {               // convw: fragment-major layout
    const int base = blk * 4096;
#pragma unroll
    for (int i = 0; i < 16; ++i) {
      int idx = base + i * 256 + t;
      int tap = idx >> 16;
      int og = (idx >> 12) & 15, kh = (idx >> 9) & 7;
      int l15o = (idx >> 5) & 15, c5 = idx & 31;
      int o = og * 16 + l15o, c = kh * 32 + c5;
      Wt[idx] = (half_t)dwconv_w[(o * 256 + c) * 9 + tap];
    }
  } else if (blk < 240) {        // qkvw (q rows pre-scaled)
    const int base = (blk - 144) * 2048;
#pragma unroll
    for (int i = 0; i < 8; ++i) {
      int idx = base + i * 256 + t;
      float v = qkv_w[idx];
      if (idx < 65536) v *= SCALEQ;
      qw16[idx] = (half_t)v;
    }
  } else if (blk < 272) {        // projw
    const int base = (blk - 240) * 2048;
#pragma unroll
    for (int i = 0; i < 8; ++i) {
      int idx = base + i * 256 + t;
      pw16[idx] = (half_t)proj_w[idx];
    }
  } else {                       // bias table btab[head][n][m]
    const int base = (blk - 272) * 2048;
#pragma unroll
    for (int i = 0; i < 8; ++i) {
      int idx = base + i * 256 + t;
      int hd = idx >> 12, n = (idx >> 6) & 63, m = idx & 63;
      int h1 = n >> 3, w1 = n & 7, h2 = m >> 3, w2 = m & 7;
      int ridx = (h1 - h2 + 7) * 15 + (w1 - w2 + 7);
      btab[idx] = rpb[ridx * 8 + hd];
    }
  }
}

// ---------------- fully fused, 3 blocks/CU (LDS 53760 B) ----------------
// grid 800, block 512 (8 waves = 1 wave per head).
// Region A [0, 33280 B) is TIME-OVERLAYED: fp32 staging tile [128][65]
// (two c-halves) -> xpl [65][256] conv input -> xlp [64][256] conv output
// (epilogue write guarded by a barrier after the conv K-loop's last xpl
// read). Region B: r11-verified 2560-B/wave time-sliced scratch. Conv B
// reads are LDS (r11 proved global-B gathers are a 2x disaster).
__global__ __launch_bounds__(512)
__attribute__((amdgpu_waves_per_eu(4))) void fused_all(
    const float* __restrict__ xg, const half_t* __restrict__ Wt,
    const float* __restrict__ convb, const half_t* __restrict__ qw,
    const float* __restrict__ qkvb, const float* __restrict__ btab,
    const half_t* __restrict__ pw, const float* __restrict__ projb,
    float* __restrict__ out32) {
  __shared__ __align__(16) half_t LS[26880];   // 53760 B
  const int bd = blockIdx.x;
  const int tid = threadIdx.x;
  const int wave = tid >> 6, lane = tid & 63;
  const int l15 = lane & 15, quad = lane >> 4;
  const int head = wave;
  const int b = bd / 100, d = bd % 100;

  half_t* xpl = LS;                          // [65][256] conv in (region A)
  half_t* xlp = LS;                          // [64][256] conv out (overlay)
  half_t* xa = LS;                           // [64][264] overlay after PV barrier
  float* T = (float*)LS;                     // [64][68] fp32 overlay at the end
  float* tile = (float*)LS;                  // [128][65] fp32 staging overlay
  half_t* buf = LS + 16640 + wave * 1280;    // 2560 B per-wave scratch

  const half_t* Wq0 = qw + head * 32 * 256;
  const half_t* Wk0 = qw + 65536 + head * 32 * 256;
  const half_t* Wv0 = qw + 131072 + head * 32 * 256;

  // ---- stage x[b,:,d,:,:] in two 128-channel halves through tile ----
  half8 xr[4];
  {
    const float* xb0 = xg + ((size_t)(b * 256) * 100 + d) * 64;
    for (int hf = 0; hf < 2; ++hf) {
#pragma unroll
      for (int i = 0; i < 16; ++i) {
        const int cl = i * 8 + wave;          // 0..127
        tile[cl * 65 + lane] = xb0[(size_t)(hf * 128 + cl) * 6400 + lane];
      }
      __syncthreads();
#pragma unroll
      for (int ii = 0; ii < 2; ++ii) {
        const int c8l = wave * 2 + ii;        // 0..15
#pragma unroll
        for (int j = 0; j < 8; ++j)
          xr[hf * 2 + ii][j] = (half_t)tile[(c8l * 8 + j) * 65 + lane];
      }
      __syncthreads();                        // tile reads done (next hf / xpl write)
    }
    // write xpl [65][256] fp16 over the tile region, conv-expected swizzle
#pragma unroll
    for (int hf = 0; hf < 2; ++hf)
#pragma unroll
      for (int ii = 0; ii < 2; ++ii) {
        const int c8 = hf * 16 + wave * 2 + ii;
        *(half8*)&xpl[lane * 256 + ((c8 ^ (lane & 7)) * 8)] = xr[hf * 2 + ii];
      }
    if (tid < 32) {                           // zero row 64 (padding source)
      half8 z = {};
      *(half8*)(xpl + 64 * 256 + tid * 8) = z;
    }
  }
  __syncthreads();

  // ---- conv implicit GEMM: wave owns o in [wave*32,+32), px 0..63 ----
  {
    const int wwl = l15 & 7, hb = l15 >> 3;
    float4v acc[2][4];
#pragma unroll
    for (int mi = 0; mi < 2; ++mi)
#pragma unroll
      for (int ni = 0; ni < 4; ++ni) {
        float4v z = {0.f, 0.f, 0.f, 0.f};
        acc[mi][ni] = z;
      }
    const half_t* wv0 = Wt + (wave * 2) * 4096 + l15 * 32 + quad * 8;
#pragma unroll 1
    for (int tap = 0; tap < 9; ++tap) {
      const int th = tap / 3, tw = tap - th * 3;
      const half_t* wt = wv0 + tap * 65536;
      const int ww = wwl + tw;
      const int okw = (ww >= 1) & (ww <= 8);
      int rowv[4];
#pragma unroll
      for (int ni = 0; ni < 4; ++ni) {
        const int hh = hb + th + ni * 2;
        const int ok = okw & (hh >= 1) & (hh <= 8);
        rowv[ni] = ok ? ((hh - 1) * 8 + (ww - 1)) : 64;   // 64 = zero row
      }
#pragma unroll
      for (int kh = 0; kh < 8; ++kh) {
        half8 af0 = *(const half8*)(wt + kh * 512);
        half8 af1 = *(const half8*)(wt + 4096 + kh * 512);
        half8 bf[4];
#pragma unroll
        for (int ni = 0; ni < 4; ++ni) {
          const int r = rowv[ni];
          bf[ni] = *(const half8*)&xpl[r * 256 + (((kh * 4 + quad) ^ (r & 7)) * 8)];
        }
#pragma unroll
        for (int ni = 0; ni < 4; ++ni) {
          acc[0][ni] = __builtin_amdgcn_mfma_f32_16x16x32_f16(af0, bf[ni], acc[0][ni], 0, 0, 0);
          acc[1][ni] = __builtin_amdgcn_mfma_f32_16x16x32_f16(af1, bf[ni], acc[1][ni], 0, 0, 0);
        }
      }
    }
    __syncthreads();   // ALL waves done reading xpl -> xlp may overlay it
    // epilogue: +bias, fp16, store xl[px][o] with the qkv-expected swizzle
#pragma unroll
    for (int mi = 0; mi < 2; ++mi) {
      const int o4 = wave * 32 + mi * 16 + quad * 4;
      const float4v b4 = *(const float4v*)&convb[o4];
      const int chunk = o4 >> 3;
      const int sub = (quad & 1) * 4;
#pragma unroll
      for (int ni = 0; ni < 4; ++ni) {
        const int px = ni * 16 + l15;
        half4v h;
        h.x = (half_t)(acc[mi][ni].x + b4.x);
        h.y = (half_t)(acc[mi][ni].y + b4.y);
        h.z = (half_t)(acc[mi][ni].z + b4.z);
        h.w = (half_t)(acc[mi][ni].w + b4.w);
        *(half4v*)&xlp[px * 256 + ((chunk ^ (px & 7)) * 8) + sub] = h;
      }
    }
  }

  __syncthreads();   // xl complete; scratch region live for tail

  // ---- q GEMM: weights per-kh direct from L2; transpose via 2 row-halves ----
  half8 aq[4];
  {
    float4v acc[2][4];
#pragma unroll
    for (int mi = 0; mi < 2; ++mi)
#pragma unroll
      for (int ni = 0; ni < 4; ++ni) {
        float4v z = {0.f, 0.f, 0.f, 0.f};
        acc[mi][ni] = z;
      }
#pragma unroll
    for (int kh = 0; kh < 8; ++kh) {
      half8 w0 = *(const half8*)(Wq0 + l15 * 256 + kh * 32 + quad * 8);
      half8 w1 = *(const half8*)(Wq0 + (16 + l15) * 256 + kh * 32 + quad * 8);
      half8 bf[4];
#pragma unroll
      for (int ni = 0; ni < 4; ++ni) {
        int r = ni * 16 + l15;
        bf[ni] = *(const half8*)&xlp[r * 256 + (((kh * 4 + quad) ^ (r & 7)) * 8)];
      }
#pragma unroll
      for (int ni = 0; ni < 4; ++ni) {
        acc[0][ni] = __builtin_amdgcn_mfma_f32_16x16x32_f16(w0, bf[ni], acc[0][ni], 0, 0, 0);
        acc[1][ni] = __builtin_amdgcn_mfma_f32_16x16x32_f16(w1, bf[ni], acc[1][ni], 0, 0, 0);
      }
    }
#pragma unroll
    for (int h2 = 0; h2 < 2; ++h2) {       // rows h2*32 .. +31 through buf[32][40]
#pragma unroll
      for (int mi = 0; mi < 2; ++mi) {
        const float4v b4 = *(const float4v*)&qkvb[head * 32 + mi * 16 + quad * 4];
#pragma unroll
        for (int nj = 0; nj < 2; ++nj) {
          const int ni = h2 * 2 + nj;
          half4v h;
          h.x = (half_t)(acc[mi][ni].x + b4.x * SCALEQ);
          h.y = (half_t)(acc[mi][ni].y + b4.y * SCALEQ);
          h.z = (half_t)(acc[mi][ni].z + b4.z * SCALEQ);
          h.w = (half_t)(acc[mi][ni].w + b4.w * SCALEQ);
          *(half4v*)(buf + (nj * 16 + l15) * 40 + mi * 16 + quad * 4) = h;
        }
      }
      WAIT_LDS();
#pragma unroll
      for (int j = 0; j < 2; ++j)
        aq[h2 * 2 + j] = *(const half8*)(buf + (j * 16 + l15) * 40 + quad * 8);
      WAIT_LDS();
    }
  }

  // ---- k GEMM (same pattern) ----
  half8 bk[4];
  {
    float4v acc[2][4];
#pragma unroll
    for (int mi = 0; mi < 2; ++mi)
#pragma unroll
      for (int ni = 0; ni < 4; ++ni) {
        float4v z = {0.f, 0.f, 0.f, 0.f};
        acc[mi][ni] = z;
      }
#pragma unroll
    for (int kh = 0; kh < 8; ++kh) {
      half8 w0 = *(const half8*)(Wk0 + l15 * 256 + kh * 32 + quad * 8);
      half8 w1 = *(const half8*)(Wk0 + (16 + l15) * 256 + kh * 32 + quad * 8);
      half8 bf[4];
#pragma unroll
      for (int ni = 0; ni < 4; ++ni) {
        int r = ni * 16 + l15;
        bf[ni] = *(const half8*)&xlp[r * 256 + (((kh * 4 + quad) ^ (r & 7)) * 8)];
      }
#pragma unroll
      for (int ni = 0; ni < 4; ++ni) {
        acc[0][ni] = __builtin_amdgcn_mfma_f32_16x16x32_f16(w0, bf[ni], acc[0][ni], 0, 0, 0);
        acc[1][ni] = __builtin_amdgcn_mfma_f32_16x16x32_f16(w1, bf[ni], acc[1][ni], 0, 0, 0);
      }
    }
#pragma unroll
    for (int h2 = 0; h2 < 2; ++h2) {
#pragma unroll
      for (int mi = 0; mi < 2; ++mi) {
        const float4v b4 = *(const float4v*)&qkvb[256 + head * 32 + mi * 16 + quad * 4];
#pragma unroll
        for (int nj = 0; nj < 2; ++nj) {
          const int ni = h2 * 2 + nj;
          half4v h;
          h.x = (half_t)(acc[mi][ni].x + b4.x);
          h.y = (half_t)(acc[mi][ni].y + b4.y);
          h.z = (half_t)(acc[mi][ni].z + b4.z);
          h.w = (half_t)(acc[mi][ni].w + b4.w);
          *(half4v*)(buf + (nj * 16 + l15) * 40 + mi * 16 + quad * 4) = h;
        }
      }
      WAIT_LDS();
#pragma unroll
      for (int j = 0; j < 2; ++j)
        bk[h2 * 2 + j] = *(const half8*)(buf + (j * 16 + l15) * 40 + quad * 8);
      WAIT_LDS();
    }
  }

  // ---- v GEMM: transpose via 2 c-halves of buf[16][72]; av straight to regs ----
  half8 av[2][2];
  {
    float4v acc[2][4];
#pragma unroll
    for (int mi = 0; mi < 2; ++mi)
#pragma unroll
      for (int ni = 0; ni < 4; ++ni) {
        float4v z = {0.f, 0.f, 0.f, 0.f};
        acc[mi][ni] = z;
      }
#pragma unroll
    for (int kh = 0; kh < 8; ++kh) {
      half8 w0 = *(const half8*)(Wv0 + l15 * 256 + kh * 32 + quad * 8);
      half8 w1 = *(const half8*)(Wv0 + (16 + l15) * 256 + kh * 32 + quad * 8);
      half8 bf[4];
#pragma unroll
      for (int ni = 0; ni < 4; ++ni) {
        int r = ni * 16 + l15;
        bf[ni] = *(const half8*)&xlp[r * 256 + (((kh * 4 + quad) ^ (r & 7)) * 8)];
      }
#pragma unroll
      for (int ni = 0; ni < 4; ++ni) {
        acc[0][ni] = __builtin_amdgcn_mfma_f32_16x16x32_f16(w0, bf[ni], acc[0][ni], 0, 0, 0);
        acc[1][ni] = __builtin_amdgcn_mfma_f32_16x16x32_f16(w1, bf[ni], acc[1][ni], 0, 0, 0);
      }
    }
#pragma unroll
    for (int mi = 0; mi < 2; ++mi) {       // c-rows mi*16 .. +15 through buf[16][72]
      const float4v b4 = *(const float4v*)&qkvb[512 + head * 32 + mi * 16 + quad * 4];
#pragma unroll
      for (int ni = 0; ni < 4; ++ni)
#pragma unroll
        for (int iv = 0; iv < 4; ++iv)
          buf[(quad * 4 + iv) * 72 + ni * 16 + l15] =
              (half_t)(acc[mi][ni][iv] + b4[iv]);
      WAIT_LDS();
#pragma unroll
      for (int k2 = 0; k2 < 2; ++k2)
        av[mi][k2] = *(const half8*)(buf + l15 * 72 + k2 * 32 + quad * 8);
      WAIT_LDS();
    }
  }

  // ---- QK^T + bias (direct loads) + softmax ----
  const float* bh = btab + head * 4096;
  float4v s[4][4];
#pragma unroll
  for (int ni = 0; ni < 4; ++ni)
#pragma unroll
    for (int mi = 0; mi < 4; ++mi) {
      float4v z = {0.f, 0.f, 0.f, 0.f};
      s[ni][mi] = __builtin_amdgcn_mfma_f32_16x16x32_f16(aq[ni], bk[mi], z, 0, 0, 0);
    }
#pragma unroll
  for (int ni = 0; ni < 4; ++ni)
#pragma unroll
    for (int i = 0; i < 4; ++i) {
      const int n = ni * 16 + quad * 4 + i;
#pragma unroll
      for (int mi = 0; mi < 4; ++mi)
        s[ni][mi][i] += bh[n * 64 + mi * 16 + l15];
    }
  float inv[4][4];
#pragma unroll
  for (int ni = 0; ni < 4; ++ni)
#pragma unroll
    for (int i = 0; i < 4; ++i) {
      float mx = fmaxf(fmaxf(s[ni][0][i], s[ni][1][i]), fmaxf(s[ni][2][i], s[ni][3][i]));
      for (int off = 1; off < 16; off <<= 1) mx = fmaxf(mx, __shfl_xor(mx, off));
      float sum = 0.f;
#pragma unroll
      for (int mi = 0; mi < 4; ++mi) {
        float e = __expf(s[ni][mi][i] - mx);
        s[ni][mi][i] = e;
        sum += e;
      }
      for (int off = 1; off < 16; off <<= 1) sum += __shfl_xor(sum, off);
      inv[ni][i] = 1.0f / sum;
    }
  // pack P to fp16 in registers: frees s before PV
  half4v ph[4][4];
#pragma unroll
  for (int ni = 0; ni < 4; ++ni)
#pragma unroll
    for (int mi = 0; mi < 4; ++mi)
#pragma unroll
      for (int i = 0; i < 4; ++i)
        ph[ni][mi][i] = (half_t)(s[ni][mi][i] * inv[ni][i]);

  // ---- PV: P through buf[32][36] in 4 (k2 x row-half) rounds ----
  float4v oa[2][4];
#pragma unroll
  for (int ci = 0; ci < 2; ++ci)
#pragma unroll
    for (int ni = 0; ni < 4; ++ni) {
      float4v z = {0.f, 0.f, 0.f, 0.f};
      oa[ci][ni] = z;
    }
#pragma unroll
  for (int k2 = 0; k2 < 2; ++k2) {
#pragma unroll
    for (int rh = 0; rh < 2; ++rh) {       // P rows rh*32 .. +31
#pragma unroll
      for (int nj = 0; nj < 2; ++nj) {
        const int ni = rh * 2 + nj;
#pragma unroll
        for (int mi2 = 0; mi2 < 2; ++mi2) {
          const int mi = k2 * 2 + mi2;
#pragma unroll
          for (int i = 0; i < 4; ++i)
            buf[(nj * 16 + quad * 4 + i) * 36 + mi2 * 16 + l15] = ph[ni][mi][i];
        }
      }
      WAIT_LDS();
      half8 bpn[2];
#pragma unroll
      for (int nj = 0; nj < 2; ++nj)
        bpn[nj] = *(const half8*)(buf + (nj * 16 + l15) * 36 + quad * 8);
      WAIT_LDS();
#pragma unroll
      for (int nj = 0; nj < 2; ++nj)
#pragma unroll
        for (int ci = 0; ci < 2; ++ci)
          oa[ci][rh * 2 + nj] = __builtin_amdgcn_mfma_f32_16x16x32_f16(
              av[ci][k2], bpn[nj], oa[ci][rh * 2 + nj], 0, 0, 0);
    }
  }

  __syncthreads();  // all waves done reading xlp/buf -> xa may overwrite

  // ---- xa -> LDS [px][264] ----
#pragma unroll
  for (int ci = 0; ci < 2; ++ci)
#pragma unroll
    for (int ni = 0; ni < 4; ++ni) {
      half4v h = {(half_t)oa[ci][ni].x, (half_t)oa[ci][ni].y,
                  (half_t)oa[ci][ni].z, (half_t)oa[ci][ni].w};
      *(half4v*)(xa + (ni * 16 + l15) * 264 + head * 32 + ci * 16 + quad * 4) = h;
    }
  __syncthreads();

  // ---- proj: wave owns o-rows [32*wave,+32), weights per-kh from L2 ----
  const half_t* Wp0 = pw + wave * 32 * 256;
  float4v pacc[2][4];
#pragma unroll
  for (int mi = 0; mi < 2; ++mi)
#pragma unroll
    for (int ni = 0; ni < 4; ++ni) {
      float4v z = {0.f, 0.f, 0.f, 0.f};
      pacc[mi][ni] = z;
    }
#pragma unroll
  for (int kh = 0; kh < 8; ++kh) {
    half8 w0 = *(const half8*)(Wp0 + l15 * 256 + kh * 32 + quad * 8);
    half8 w1 = *(const half8*)(Wp0 + (16 + l15) * 256 + kh * 32 + quad * 8);
    half8 bf[4];
#pragma unroll
    for (int ni = 0; ni < 4; ++ni)
      bf[ni] = *(const half8*)&xa[(ni * 16 + l15) * 264 + kh * 32 + quad * 8];
#pragma unroll
    for (int ni = 0; ni < 4; ++ni) {
      pacc[0][ni] = __builtin_amdgcn_mfma_f32_16x16x32_f16(w0, bf[ni], pacc[0][ni], 0, 0, 0);
      pacc[1][ni] = __builtin_amdgcn_mfma_f32_16x16x32_f16(w1, bf[ni], pacc[1][ni], 0, 0, 0);
    }
  }
#pragma unroll
  for (int mi = 0; mi < 2; ++mi) {
    const float4v b4 = *(const float4v*)&projb[wave * 32 + mi * 16 + quad * 4];
#pragma unroll
    for (int ni = 0; ni < 4; ++ni) {
      pacc[mi][ni].x += b4.x;
      pacc[mi][ni].y += b4.y;
      pacc[mi][ni].z += b4.z;
      pacc[mi][ni].w += b4.w;
    }
  }

  // ---- transpose epilogue: 4 rounds of 64 o-rows via T[64][68] fp32 ----
  const size_t bdbase = (size_t)b * 1638400 + (size_t)d * 64;
  const int tr = tid >> 3;             // 0..63
  const int col0 = (tid & 7) * 4;      // 0..28
  for (int r = 0; r < 4; ++r) {
    __syncthreads();                   // r=0: also guards xa reads done
    if ((wave >> 1) == r) {
      const int rb = (wave & 1) * 32;
#pragma unroll
      for (int mi = 0; mi < 2; ++mi)
#pragma unroll
        for (int ni = 0; ni < 4; ++ni)
#pragma unroll
          for (int iv = 0; iv < 4; ++iv)
            T[(rb + mi * 16 + quad * 4 + iv) * 68 + ni * 16 + l15] = pacc[mi][ni][iv];
    }
    __syncthreads();
    const int o = r * 64 + tr;
    float* dst = out32 + bdbase + (size_t)o * 6400 + col0;
    const float* srcT = &T[tr * 68 + col0];
    float4v v0 = *(const float4v*)srcT;
    float4v v1 = *(const float4v*)(srcT + 32);
    __builtin_nontemporal_store(v0, (float4v*)dst);
    __builtin_nontemporal_store(v1, (float4v*)(dst + 32));
  }
}

// ---------------- launch ----------------
extern "C" void kernel_launch(void* const* d_in, const int* in_sizes, int n_in,
                              void* d_out, int out_size, void* d_ws, size_t ws_size,
                              hipStream_t stream) {
  const float* x        = (const float*)d_in[0];
  const float* dwconv_w = (const float*)d_in[1];
  const float* dwconv_b = (const float*)d_in[2];
  const float* qkv_w    = (const float*)d_in[3];
  const float* qkv_b    = (const float*)d_in[4];
  const float* proj_w   = (const float*)d_in[5];
  const float* proj_b   = (const float*)d_in[6];
  const float* rpb      = (const float*)d_in[7];
  float* out = (float*)d_out;

  char* ws = (char*)d_ws;
  size_t off = 0;
  half_t* Wt   = (half_t*)(ws + off); off += 1179648;    // [9][16og][8kh][16][32]
  half_t* qw16 = (half_t*)(ws + off); off += 393216;
  half_t* pw16 = (half_t*)(ws + off); off += 131072;
  float*  btab = (float*)(ws + off);  off += 131072;     // [8][64][64]

  prep_w<<<288, 256, 0, stream>>>(dwconv_w, qkv_w, proj_w, rpb,
                                  Wt, qw16, pw16, btab);
  fused_all<<<800, 512, 0, stream>>>(x, Wt, dwconv_b, qw16, qkv_b, btab,
                                     pw16, proj_b, out);
}